// Round 1
// baseline (148.478 us; speedup 1.0000x reference)
//
#include <hip/hip_runtime.h>

// Problem dims (hardcoded per reference setup_inputs):
//   x:   (8, 64, 64, 64)  fp32
//   ref: (8, 64, 128, 128) fp32
//   out: (8, 64, 128, 128) fp32
#define B   8
#define C   64     // channels (in == out == 64)
#define HI  64     // x spatial
#define WI  64
#define HO  128    // ref/out spatial
#define WO  128

__device__ __forceinline__ float relu(float v) { return v > 0.f ? v : 0.f; }

// ---------------------------------------------------------------------------
// Kernel 1: y1 = relu(scale1 * (W1 @ x) + bias1)   (1x1 conv + BN + ReLU)
// grid: B*HI blocks, 256 threads. Each block does one (b,h) row: 64o x 64w.
// Thread tile: 4o x 4w (16 outputs). LDS-staged x row + transposed W1.
// ---------------------------------------------------------------------------
__global__ __launch_bounds__(256) void k_conv1(
    const float* __restrict__ x, const float* __restrict__ w1,
    const float* __restrict__ cb, const float* __restrict__ g,
    const float* __restrict__ bb, const float* __restrict__ mm,
    const float* __restrict__ vv, float* __restrict__ y1) {
  __shared__ float xs[C][WI];        // [c][w]
  __shared__ float w1t[C][68];       // [c][o], padded stride 68 (16B aligned, no bank conflict)
  __shared__ float s_sc[C], s_bs[C];

  const int blk = blockIdx.x;        // b*HI + h
  const int b = blk >> 6, h = blk & 63;
  const int tid = threadIdx.x;

  const float* xrow = x + (size_t)b * C * (HI * WI) + h * WI;
  for (int i = tid; i < C * WI; i += 256) {
    const int c = i >> 6, w = i & 63;
    xs[c][w] = xrow[(size_t)c * (HI * WI) + w];
    w1t[i & 63][i >> 6] = w1[i];     // w1[o][c] -> w1t[c][o]
  }
  if (tid < C) {
    const float s = g[tid] * rsqrtf(vv[tid] + 1e-5f);
    s_sc[tid] = s;
    s_bs[tid] = cb[tid] * s + bb[tid] - mm[tid] * s;
  }
  __syncthreads();

  const int wt = tid & 15;           // w4 = wt*4
  const int ot = tid >> 4;           // o4 = ot*4
  float acc[4][4] = {{0.f}};

#pragma unroll 4
  for (int c = 0; c < C; ++c) {
    const float4 r = *(const float4*)&xs[c][wt * 4];
    const float4 a = *(const float4*)&w1t[c][ot * 4];
    acc[0][0] += a.x * r.x; acc[0][1] += a.x * r.y; acc[0][2] += a.x * r.z; acc[0][3] += a.x * r.w;
    acc[1][0] += a.y * r.x; acc[1][1] += a.y * r.y; acc[1][2] += a.y * r.z; acc[1][3] += a.y * r.w;
    acc[2][0] += a.z * r.x; acc[2][1] += a.z * r.y; acc[2][2] += a.z * r.z; acc[2][3] += a.z * r.w;
    acc[3][0] += a.w * r.x; acc[3][1] += a.w * r.y; acc[3][2] += a.w * r.z; acc[3][3] += a.w * r.w;
  }

  float* yb = y1 + (size_t)(b * C + ot * 4) * (HI * WI) + h * WI + wt * 4;
#pragma unroll
  for (int j = 0; j < 4; ++j) {
    const int o = ot * 4 + j;
    float4 v;
    v.x = relu(acc[j][0] * s_sc[o] + s_bs[o]);
    v.y = relu(acc[j][1] * s_sc[o] + s_bs[o]);
    v.z = relu(acc[j][2] * s_sc[o] + s_bs[o]);
    v.w = relu(acc[j][3] * s_sc[o] + s_bs[o]);
    *(float4*)(yb + (size_t)j * (HI * WI)) = v;
  }
}

// ---------------------------------------------------------------------------
// Kernel 2: res = mean over channels of ref.  grid: B*HO*WO/256 blocks.
// ---------------------------------------------------------------------------
__global__ __launch_bounds__(256) void k_res(
    const float* __restrict__ ref, float* __restrict__ res) {
  const int p = blockIdx.x * 256 + threadIdx.x;   // b*HO*WO + h*WO + w
  const int b = p >> 14;                          // HO*WO = 16384
  const int r = p & 16383;
  const float* pp = ref + (size_t)b * C * (HO * WO) + r;
  float s0 = 0.f, s1 = 0.f, s2 = 0.f, s3 = 0.f;
#pragma unroll
  for (int c = 0; c < C; c += 4) {
    s0 += pp[(size_t)(c + 0) * (HO * WO)];
    s1 += pp[(size_t)(c + 1) * (HO * WO)];
    s2 += pp[(size_t)(c + 2) * (HO * WO)];
    s3 += pp[(size_t)(c + 3) * (HO * WO)];
  }
  res[p] = ((s0 + s1) + (s2 + s3)) * (1.0f / 64.0f);
}

// ---------------------------------------------------------------------------
// Kernel 3 (main): per (b,h) output row.
//  - mask from res neighborhood -> 4 corner weights + invden per pixel
//    (nearest-2x upsample means the 9 taps hit only 4 distinct y1 values)
//  - conv2(ref) via LDS-tiled matvec (8o x 4w register tile per thread)
//  - out = num*invden + relu(scale2*conv2 + bias2)
// ---------------------------------------------------------------------------
__global__ __launch_bounds__(256) void k_main(
    const float* __restrict__ ref, const float* __restrict__ res,
    const float* __restrict__ y1, const float* __restrict__ w2,
    const float* __restrict__ cb, const float* __restrict__ g,
    const float* __restrict__ bb, const float* __restrict__ mm,
    const float* __restrict__ vv, float* __restrict__ out) {
  __shared__ float refs[C][WO];      // 32 KB [c][w]
  __shared__ float w2t[C][68];       // 17 KB [c][o] padded
  __shared__ float resr[3][WO + 2];  // res rows h-1,h,h+1 with zero pad cols
  __shared__ float s_sc[C], s_bs[C];
  __shared__ float s_wc[4][WO];      // per-pixel corner weights (SoA)
  __shared__ float s_inv[WO];        // per-pixel 1/(den+1e-6)

  const int blk = blockIdx.x;        // b*HO + h
  const int b = blk >> 7, h = blk & 127;
  const int tid = threadIdx.x;

  const float* refrow = ref + (size_t)b * C * (HO * WO) + h * WO;
  for (int i = tid; i < C * WO; i += 256) {
    const int c = i >> 7, w = i & 127;
    refs[c][w] = refrow[(size_t)c * (HO * WO) + w];
  }
  for (int i = tid; i < C * C; i += 256)
    w2t[i & 63][i >> 6] = w2[i];     // w2[o][c] -> w2t[c][o]
  if (tid < C) {
    const float s = g[tid] * rsqrtf(vv[tid] + 1e-5f);
    s_sc[tid] = s;
    s_bs[tid] = cb[tid] * s + bb[tid] - mm[tid] * s;
  }
  {
    const float* resb = res + (size_t)b * (HO * WO);
    for (int i = tid; i < 3 * (WO + 2); i += 256) {
      const int rr = i / (WO + 2), cc = i % (WO + 2);
      const int hh = h + rr - 1, ww = cc - 1;
      float v = 0.f;
      if (hh >= 0 && hh < HO && ww >= 0 && ww < WO)
        v = resb[hh * WO + ww];
      resr[rr][cc] = v;
    }
  }
  __syncthreads();

  const int rlo = (h >= 1) ? ((h - 1) >> 1) : 0;

  // Phase 1: per-pixel mask -> corner weights (threads 0..127)
  if (tid < WO) {
    const int w = tid;
    float u[9];
#pragma unroll
    for (int dh = 0; dh < 3; ++dh)
#pragma unroll
      for (int dw = 0; dw < 3; ++dw)
        u[dh * 3 + dw] = resr[dh][w + dw];
    float sum = u[0];
#pragma unroll
    for (int k = 1; k < 9; ++k) sum += u[k];
    const float ua = sum * (1.f / 9.f);
    const bool ui = (u[4] - ua) > 0.f;

    const int clo = (w >= 1) ? ((w - 1) >> 1) : 0;
    float den = 0.f;
    float wc0 = 0.f, wc1 = 0.f, wc2 = 0.f, wc3 = 0.f;
#pragma unroll
    for (int dh = 0; dh < 3; ++dh) {
      const int hh = h + dh - 1;
      const bool hv = (hh >= 0) && (hh < HO);
      const int rs = hv ? ((hh >> 1) - rlo) : 0;
#pragma unroll
      for (int dw = 0; dw < 3; ++dw) {
        const bool up = (u[dh * 3 + dw] - ua) > 0.f;
        const float mk = (up == ui) ? 1.f : 0.f;
        den += mk;
        const int ww = w + dw - 1;
        const bool wv = (ww >= 0) && (ww < WO);
        const int cs = wv ? ((ww >> 1) - clo) : 0;
        const float t = (hv && wv) ? mk : 0.f;
        const float t0 = (rs == 0) ? t : 0.f;
        const float t1 = (rs == 1) ? t : 0.f;
        wc0 += (cs == 0) ? t0 : 0.f;
        wc1 += (cs == 1) ? t0 : 0.f;
        wc2 += (cs == 0) ? t1 : 0.f;
        wc3 += (cs == 1) ? t1 : 0.f;
      }
    }
    s_wc[0][w] = wc0; s_wc[1][w] = wc1; s_wc[2][w] = wc2; s_wc[3][w] = wc3;
    s_inv[w] = 1.f / (den + 1e-6f);
  }
  __syncthreads();

  // Phase 2: conv2 matvec + fused epilogue. Thread tile: 8o x 4w.
  const int wt = tid & 31;           // w4 = wt*4
  const int ot = tid >> 5;           // o8 = ot*8
  const int w4 = wt * 4;

  const float4 wcv0 = *(const float4*)&s_wc[0][w4];
  const float4 wcv1 = *(const float4*)&s_wc[1][w4];
  const float4 wcv2 = *(const float4*)&s_wc[2][w4];
  const float4 wcv3 = *(const float4*)&s_wc[3][w4];
  const float4 invv = *(const float4*)&s_inv[w4];

  int r1 = rlo + 1; if (r1 > HI - 1) r1 = HI - 1;
  int clo[4], c1[4];
#pragma unroll
  for (int j = 0; j < 4; ++j) {
    const int w = w4 + j;
    clo[j] = (w >= 1) ? ((w - 1) >> 1) : 0;
    c1[j] = clo[j] + 1; if (c1[j] > WI - 1) c1[j] = WI - 1;
  }

  float acc[8][4] = {{0.f}};
#pragma unroll 2
  for (int c = 0; c < C; ++c) {
    const float4 r = *(const float4*)&refs[c][w4];
    const float4 a = *(const float4*)&w2t[c][ot * 8];
    const float4 q = *(const float4*)&w2t[c][ot * 8 + 4];
    acc[0][0] += a.x * r.x; acc[0][1] += a.x * r.y; acc[0][2] += a.x * r.z; acc[0][3] += a.x * r.w;
    acc[1][0] += a.y * r.x; acc[1][1] += a.y * r.y; acc[1][2] += a.y * r.z; acc[1][3] += a.y * r.w;
    acc[2][0] += a.z * r.x; acc[2][1] += a.z * r.y; acc[2][2] += a.z * r.z; acc[2][3] += a.z * r.w;
    acc[3][0] += a.w * r.x; acc[3][1] += a.w * r.y; acc[3][2] += a.w * r.z; acc[3][3] += a.w * r.w;
    acc[4][0] += q.x * r.x; acc[4][1] += q.x * r.y; acc[4][2] += q.x * r.z; acc[4][3] += q.x * r.w;
    acc[5][0] += q.y * r.x; acc[5][1] += q.y * r.y; acc[5][2] += q.y * r.z; acc[5][3] += q.y * r.w;
    acc[6][0] += q.z * r.x; acc[6][1] += q.z * r.y; acc[6][2] += q.z * r.z; acc[6][3] += q.z * r.w;
    acc[7][0] += q.w * r.x; acc[7][1] += q.w * r.y; acc[7][2] += q.w * r.z; acc[7][3] += q.w * r.w;
  }

  const float* y1b = y1 + (size_t)(b * C + ot * 8) * (HI * WI);
  float* outb = out + (size_t)(b * C + ot * 8) * (HO * WO) + h * WO + w4;
#pragma unroll
  for (int j = 0; j < 8; ++j) {
    const int o = ot * 8 + j;
    const float* r0p = y1b + (size_t)j * (HI * WI) + rlo * WI;
    const float* r1p = y1b + (size_t)j * (HI * WI) + r1 * WI;

    const float n0 = wcv0.x * r0p[clo[0]] + wcv1.x * r0p[c1[0]] + wcv2.x * r1p[clo[0]] + wcv3.x * r1p[c1[0]];
    const float n1 = wcv0.y * r0p[clo[1]] + wcv1.y * r0p[c1[1]] + wcv2.y * r1p[clo[1]] + wcv3.y * r1p[c1[1]];
    const float n2 = wcv0.z * r0p[clo[2]] + wcv1.z * r0p[c1[2]] + wcv2.z * r1p[clo[2]] + wcv3.z * r1p[c1[2]];
    const float n3 = wcv0.w * r0p[clo[3]] + wcv1.w * r0p[c1[3]] + wcv2.w * r1p[clo[3]] + wcv3.w * r1p[c1[3]];

    float4 v;
    v.x = n0 * invv.x + relu(acc[j][0] * s_sc[o] + s_bs[o]);
    v.y = n1 * invv.y + relu(acc[j][1] * s_sc[o] + s_bs[o]);
    v.z = n2 * invv.z + relu(acc[j][2] * s_sc[o] + s_bs[o]);
    v.w = n3 * invv.w + relu(acc[j][3] * s_sc[o] + s_bs[o]);
    *(float4*)(outb + (size_t)j * (HO * WO)) = v;
  }
}

// ---------------------------------------------------------------------------
extern "C" void kernel_launch(void* const* d_in, const int* in_sizes, int n_in,
                              void* d_out, int out_size, void* d_ws, size_t ws_size,
                              hipStream_t stream) {
  (void)in_sizes; (void)n_in; (void)out_size; (void)ws_size;
  const float* x   = (const float*)d_in[0];
  const float* ref = (const float*)d_in[1];
  const float* w1  = (const float*)d_in[2];
  const float* c1b = (const float*)d_in[3];
  const float* g1  = (const float*)d_in[4];
  const float* b1  = (const float*)d_in[5];
  const float* m1  = (const float*)d_in[6];
  const float* v1  = (const float*)d_in[7];
  const float* w2  = (const float*)d_in[8];
  const float* c2b = (const float*)d_in[9];
  const float* g2  = (const float*)d_in[10];
  const float* b2  = (const float*)d_in[11];
  const float* m2  = (const float*)d_in[12];
  const float* v2  = (const float*)d_in[13];
  float* out = (float*)d_out;

  float* y1  = (float*)d_ws;                       // 8*64*64*64 = 2,097,152 floats (8 MB)
  float* res = y1 + (size_t)B * C * HI * WI;       // 8*128*128 = 131,072 floats (0.5 MB)

  k_conv1<<<B * HI, 256, 0, stream>>>(x, w1, c1b, g1, b1, m1, v1, y1);
  k_res<<<(B * HO * WO) / 256, 256, 0, stream>>>(ref, res);
  k_main<<<B * HO, 256, 0, stream>>>(ref, res, y1, w2, c2b, g2, b2, m2, v2, out);
}

// Round 2
// 141.802 us; speedup vs baseline: 1.0471x; 1.0471x over previous
//
#include <hip/hip_runtime.h>

// Problem dims (hardcoded per reference setup_inputs):
//   x:   (8, 64, 64, 64)  fp32
//   ref: (8, 64, 128, 128) fp32
//   out: (8, 64, 128, 128) fp32
#define B   8
#define C   64
#define HI  64
#define WI  64
#define HO  128
#define WO  128

__device__ __forceinline__ float relu(float v) { return v > 0.f ? v : 0.f; }

// ---------------------------------------------------------------------------
// Kernel 1 (fused pre-pass):
//   blocks [0,512):   y1 = relu(scale1*(W1@x)+bias1)   one (b,h) row per block
//   blocks [512,640): res = channel-mean of ref, float4-vectorized
// Grid-level fusion overlaps the VALU-bound conv1 with the HBM-bound mean.
// ---------------------------------------------------------------------------
__global__ __launch_bounds__(256) void k_pre(
    const float* __restrict__ x, const float* __restrict__ w1,
    const float* __restrict__ cb, const float* __restrict__ g,
    const float* __restrict__ bb, const float* __restrict__ mm,
    const float* __restrict__ vv, const float* __restrict__ ref,
    float* __restrict__ y1, float* __restrict__ res) {
  __shared__ float xs[C][WI];        // 16 KB
  __shared__ float w1t[C][68];       // 17 KB, padded stride
  __shared__ float s_sc[C], s_bs[C];

  const int tid = threadIdx.x;

  if (blockIdx.x >= 512) {           // ---- res part ----
    const int p = ((blockIdx.x - 512) * 256 + tid) * 4;   // 4 px / thread
    const int b = p >> 14;                                // HO*WO = 16384
    const int r = p & 16383;
    const float* pp = ref + (size_t)b * C * (HO * WO) + r;
    float4 s0 = {0.f, 0.f, 0.f, 0.f}, s1 = {0.f, 0.f, 0.f, 0.f};
#pragma unroll
    for (int c = 0; c < C; c += 2) {
      const float4 a = *(const float4*)&pp[(size_t)c * (HO * WO)];
      const float4 d = *(const float4*)&pp[(size_t)(c + 1) * (HO * WO)];
      s0.x += a.x; s0.y += a.y; s0.z += a.z; s0.w += a.w;
      s1.x += d.x; s1.y += d.y; s1.z += d.z; s1.w += d.w;
    }
    float4 o;
    o.x = (s0.x + s1.x) * (1.f / 64.f);
    o.y = (s0.y + s1.y) * (1.f / 64.f);
    o.z = (s0.z + s1.z) * (1.f / 64.f);
    o.w = (s0.w + s1.w) * (1.f / 64.f);
    *(float4*)&res[p] = o;
    return;
  }

  // ---- conv1 part ----
  const int blk = blockIdx.x;        // b*HI + h
  const int b = blk >> 6, h = blk & 63;

  const float* xrow = x + (size_t)b * C * (HI * WI) + h * WI;
  for (int i = tid; i < C * WI; i += 256) {
    const int c = i >> 6, w = i & 63;
    xs[c][w] = xrow[(size_t)c * (HI * WI) + w];
    w1t[i & 63][i >> 6] = w1[i];     // w1[o][c] -> w1t[c][o]
  }
  if (tid < C) {
    const float s = g[tid] * rsqrtf(vv[tid] + 1e-5f);
    s_sc[tid] = s;
    s_bs[tid] = cb[tid] * s + bb[tid] - mm[tid] * s;
  }
  __syncthreads();

  const int wt = tid & 15;           // w4 = wt*4
  const int ot = tid >> 4;           // o4 = ot*4
  float acc[4][4] = {{0.f}};

#pragma unroll 4
  for (int c = 0; c < C; ++c) {
    const float4 r = *(const float4*)&xs[c][wt * 4];
    const float4 a = *(const float4*)&w1t[c][ot * 4];
    acc[0][0] += a.x * r.x; acc[0][1] += a.x * r.y; acc[0][2] += a.x * r.z; acc[0][3] += a.x * r.w;
    acc[1][0] += a.y * r.x; acc[1][1] += a.y * r.y; acc[1][2] += a.y * r.z; acc[1][3] += a.y * r.w;
    acc[2][0] += a.z * r.x; acc[2][1] += a.z * r.y; acc[2][2] += a.z * r.z; acc[2][3] += a.z * r.w;
    acc[3][0] += a.w * r.x; acc[3][1] += a.w * r.y; acc[3][2] += a.w * r.z; acc[3][3] += a.w * r.w;
  }

  float* yb = y1 + (size_t)(b * C + ot * 4) * (HI * WI) + h * WI + wt * 4;
#pragma unroll
  for (int j = 0; j < 4; ++j) {
    const int o = ot * 4 + j;
    float4 v;
    v.x = relu(acc[j][0] * s_sc[o] + s_bs[o]);
    v.y = relu(acc[j][1] * s_sc[o] + s_bs[o]);
    v.z = relu(acc[j][2] * s_sc[o] + s_bs[o]);
    v.w = relu(acc[j][3] * s_sc[o] + s_bs[o]);
    *(float4*)(yb + (size_t)j * (HI * WI)) = v;
  }
}

// ---------------------------------------------------------------------------
// Kernel 2 (main): one (b,h,half) 64-pixel half-row per block. 2048 blocks.
// LDS ~36 KB -> 4 blocks/CU (16 waves/CU) vs 2 with the full-row version.
//  - phase 1: mask -> 4 corner weights + invden per pixel (64 threads)
//  - phase 2: conv2 matvec 4o x 4w register tile + fused masked-upsample
//    epilogue (y1 gather is L1-resident: 17 KB row-pair per block)
// ---------------------------------------------------------------------------
__global__ __launch_bounds__(256) void k_main(
    const float* __restrict__ ref, const float* __restrict__ res,
    const float* __restrict__ y1, const float* __restrict__ w2,
    const float* __restrict__ cb, const float* __restrict__ g,
    const float* __restrict__ bb, const float* __restrict__ mm,
    const float* __restrict__ vv, float* __restrict__ out) {
  __shared__ float refs[C][WI];      // 16 KB [c][lw]
  __shared__ float w2t[C][68];       // 17 KB [c][o] padded
  __shared__ float resr[3][WI + 2];  // res rows h-1,h,h+1 (66 cols)
  __shared__ float s_sc[C], s_bs[C];
  __shared__ float s_wc[4][WI];      // corner weights (SoA)
  __shared__ float s_inv[WI];        // 1/(den+1e-6)

  const int blk = blockIdx.x;        // b*256 + h*2 + half
  const int b = blk >> 8;
  const int h = (blk >> 1) & 127;
  const int w0 = (blk & 1) << 6;
  const int tid = threadIdx.x;

  const float* refrow = ref + (size_t)b * C * (HO * WO) + h * WO + w0;
  for (int i = tid; i < C * (WI / 4); i += 256) {       // 1024 float4
    const int c = i >> 4, w = (i & 15) * 4;
    *(float4*)&refs[c][w] = *(const float4*)&refrow[(size_t)c * (HO * WO) + w];
  }
  for (int i = tid; i < C * C; i += 256)
    w2t[i & 63][i >> 6] = w2[i];     // w2[o][c] -> w2t[c][o]
  if (tid < C) {
    const float s = g[tid] * rsqrtf(vv[tid] + 1e-5f);
    s_sc[tid] = s;
    s_bs[tid] = cb[tid] * s + bb[tid] - mm[tid] * s;
  }
  {
    const float* resb = res + (size_t)b * (HO * WO);
    for (int i = tid; i < 3 * (WI + 2); i += 256) {
      const int rr = i / (WI + 2), cc = i % (WI + 2);
      const int hh = h + rr - 1, ww = w0 + cc - 1;
      float v = 0.f;
      if (hh >= 0 && hh < HO && ww >= 0 && ww < WO)
        v = resb[hh * WO + ww];
      resr[rr][cc] = v;
    }
  }
  __syncthreads();

  const int rlo = (h >= 1) ? ((h - 1) >> 1) : 0;

  // Phase 1: per-pixel mask -> corner weights (threads 0..63)
  if (tid < WI) {
    const int lw = tid, w = w0 + lw;
    float u[9];
#pragma unroll
    for (int dh = 0; dh < 3; ++dh)
#pragma unroll
      for (int dw = 0; dw < 3; ++dw)
        u[dh * 3 + dw] = resr[dh][lw + dw];
    float sum = u[0];
#pragma unroll
    for (int k = 1; k < 9; ++k) sum += u[k];
    const float ua = sum * (1.f / 9.f);
    const bool ui = (u[4] - ua) > 0.f;

    const int clo = (w >= 1) ? ((w - 1) >> 1) : 0;
    float den = 0.f;
    float wc0 = 0.f, wc1 = 0.f, wc2 = 0.f, wc3 = 0.f;
#pragma unroll
    for (int dh = 0; dh < 3; ++dh) {
      const int hh = h + dh - 1;
      const bool hv = (hh >= 0) && (hh < HO);
      const int rs = hv ? ((hh >> 1) - rlo) : 0;
#pragma unroll
      for (int dw = 0; dw < 3; ++dw) {
        const bool up = (u[dh * 3 + dw] - ua) > 0.f;
        const float mk = (up == ui) ? 1.f : 0.f;
        den += mk;
        const int ww = w + dw - 1;
        const bool wv = (ww >= 0) && (ww < WO);
        const int cs = wv ? ((ww >> 1) - clo) : 0;
        const float t = (hv && wv) ? mk : 0.f;
        const float t0 = (rs == 0) ? t : 0.f;
        const float t1 = (rs == 1) ? t : 0.f;
        wc0 += (cs == 0) ? t0 : 0.f;
        wc1 += (cs == 1) ? t0 : 0.f;
        wc2 += (cs == 0) ? t1 : 0.f;
        wc3 += (cs == 1) ? t1 : 0.f;
      }
    }
    s_wc[0][lw] = wc0; s_wc[1][lw] = wc1; s_wc[2][lw] = wc2; s_wc[3][lw] = wc3;
    s_inv[lw] = 1.f / (den + 1e-6f);
  }
  __syncthreads();

  // Phase 2: conv2 matvec + fused epilogue. Thread tile: 4o x 4w.
  const int lw4 = (tid & 15) * 4;
  const int ot = tid >> 4;           // o4 = ot*4

  const float4 wcv0 = *(const float4*)&s_wc[0][lw4];
  const float4 wcv1 = *(const float4*)&s_wc[1][lw4];
  const float4 wcv2 = *(const float4*)&s_wc[2][lw4];
  const float4 wcv3 = *(const float4*)&s_wc[3][lw4];
  const float4 invv = *(const float4*)&s_inv[lw4];

  int r1 = rlo + 1; if (r1 > HI - 1) r1 = HI - 1;
  int clo[4], c1[4];
#pragma unroll
  for (int j = 0; j < 4; ++j) {
    const int w = w0 + lw4 + j;
    clo[j] = (w >= 1) ? ((w - 1) >> 1) : 0;
    c1[j] = clo[j] + 1; if (c1[j] > WI - 1) c1[j] = WI - 1;
  }

  float acc[4][4] = {{0.f}};
#pragma unroll 4
  for (int c = 0; c < C; ++c) {
    const float4 r = *(const float4*)&refs[c][lw4];
    const float4 a = *(const float4*)&w2t[c][ot * 4];
    acc[0][0] += a.x * r.x; acc[0][1] += a.x * r.y; acc[0][2] += a.x * r.z; acc[0][3] += a.x * r.w;
    acc[1][0] += a.y * r.x; acc[1][1] += a.y * r.y; acc[1][2] += a.y * r.z; acc[1][3] += a.y * r.w;
    acc[2][0] += a.z * r.x; acc[2][1] += a.z * r.y; acc[2][2] += a.z * r.z; acc[2][3] += a.z * r.w;
    acc[3][0] += a.w * r.x; acc[3][1] += a.w * r.y; acc[3][2] += a.w * r.z; acc[3][3] += a.w * r.w;
  }

  const float* y1b = y1 + (size_t)(b * C + ot * 4) * (HI * WI);
  float* outb = out + (size_t)(b * C + ot * 4) * (HO * WO) + h * WO + w0 + lw4;
#pragma unroll
  for (int j = 0; j < 4; ++j) {
    const int o = ot * 4 + j;
    const float* r0p = y1b + (size_t)j * (HI * WI) + rlo * WI;
    const float* r1p = y1b + (size_t)j * (HI * WI) + r1 * WI;

    const float n0 = wcv0.x * r0p[clo[0]] + wcv1.x * r0p[c1[0]] + wcv2.x * r1p[clo[0]] + wcv3.x * r1p[c1[0]];
    const float n1 = wcv0.y * r0p[clo[1]] + wcv1.y * r0p[c1[1]] + wcv2.y * r1p[clo[1]] + wcv3.y * r1p[c1[1]];
    const float n2 = wcv0.z * r0p[clo[2]] + wcv1.z * r0p[c1[2]] + wcv2.z * r1p[clo[2]] + wcv3.z * r1p[c1[2]];
    const float n3 = wcv0.w * r0p[clo[3]] + wcv1.w * r0p[c1[3]] + wcv2.w * r1p[clo[3]] + wcv3.w * r1p[c1[3]];

    float4 v;
    v.x = n0 * invv.x + relu(acc[j][0] * s_sc[o] + s_bs[o]);
    v.y = n1 * invv.y + relu(acc[j][1] * s_sc[o] + s_bs[o]);
    v.z = n2 * invv.z + relu(acc[j][2] * s_sc[o] + s_bs[o]);
    v.w = n3 * invv.w + relu(acc[j][3] * s_sc[o] + s_bs[o]);
    *(float4*)(outb + (size_t)j * (HO * WO)) = v;
  }
}

// ---------------------------------------------------------------------------
extern "C" void kernel_launch(void* const* d_in, const int* in_sizes, int n_in,
                              void* d_out, int out_size, void* d_ws, size_t ws_size,
                              hipStream_t stream) {
  (void)in_sizes; (void)n_in; (void)out_size; (void)ws_size;
  const float* x   = (const float*)d_in[0];
  const float* ref = (const float*)d_in[1];
  const float* w1  = (const float*)d_in[2];
  const float* c1b = (const float*)d_in[3];
  const float* g1  = (const float*)d_in[4];
  const float* b1  = (const float*)d_in[5];
  const float* m1  = (const float*)d_in[6];
  const float* v1  = (const float*)d_in[7];
  const float* w2  = (const float*)d_in[8];
  const float* c2b = (const float*)d_in[9];
  const float* g2  = (const float*)d_in[10];
  const float* b2  = (const float*)d_in[11];
  const float* m2  = (const float*)d_in[12];
  const float* v2  = (const float*)d_in[13];
  float* out = (float*)d_out;

  float* y1  = (float*)d_ws;                       // 8 MB
  float* res = y1 + (size_t)B * C * HI * WI;       // 0.5 MB

  k_pre<<<512 + 128, 256, 0, stream>>>(x, w1, c1b, g1, b1, m1, v1, ref, y1, res);
  k_main<<<B * HO * 2, 256, 0, stream>>>(ref, res, y1, w2, c2b, g2, b2, m2, v2, out);
}

// Round 3
// 140.078 us; speedup vs baseline: 1.0600x; 1.0123x over previous
//
#include <hip/hip_runtime.h>

// Problem dims (hardcoded per reference setup_inputs):
//   x:   (8, 64, 64, 64)  fp32
//   ref: (8, 64, 128, 128) fp32
//   out: (8, 64, 128, 128) fp32
#define B   8
#define C   64
#define HI  64
#define WI  64
#define HO  128
#define WO  128

using short8 = __attribute__((ext_vector_type(8))) short;
using f32x4  = __attribute__((ext_vector_type(4))) float;
using i32x4  = __attribute__((ext_vector_type(4))) int;

__device__ __forceinline__ float relu(float v) { return v > 0.f ? v : 0.f; }

// round-to-nearest-even f32 -> bf16 (low 16 bits of result)
__device__ __forceinline__ unsigned bf16rne(float x) {
  unsigned u = __float_as_uint(x);
  u += 0x7FFFu + ((u >> 16) & 1u);
  return u >> 16;
}
// pack two f32 -> bf16 pair (lo in bits [15:0], hi in bits [31:16])
__device__ __forceinline__ unsigned packbf(float lo, float hi) {
  unsigned ua = __float_as_uint(lo); ua += 0x7FFFu + ((ua >> 16) & 1u);
  unsigned ub = __float_as_uint(hi); ub += 0x7FFFu + ((ub >> 16) & 1u);
  return (ua >> 16) | (ub & 0xFFFF0000u);
}

// ---------------------------------------------------------------------------
// Kernel 1 (fused pre-pass):
//   blocks [0,512):   y1 = relu(W1s @ x + bs1) via bf16 MFMA, one (b,h) row
//   blocks [512,640): res = channel-mean of ref, float4-vectorized
// ---------------------------------------------------------------------------
__global__ __launch_bounds__(256) void k_pre(
    const float* __restrict__ x, const float* __restrict__ w1,
    const float* __restrict__ cb, const float* __restrict__ g,
    const float* __restrict__ bb, const float* __restrict__ mm,
    const float* __restrict__ vv, const float* __restrict__ ref,
    float* __restrict__ y1, float* __restrict__ res) {
  __shared__ unsigned xP[32][68];    // c-pair-packed bf16 x row [c/2][w]
  __shared__ unsigned short W1s[64][72];  // scale-folded bf16 W1 [o][c]
  __shared__ float s_bs1[64];

  const int tid = threadIdx.x;

  if (blockIdx.x >= 512) {           // ---- res part (HBM-bound) ----
    const int p = ((blockIdx.x - 512) * 256 + tid) * 4;
    const int b = p >> 14;           // HO*WO = 16384
    const int r = p & 16383;
    const float* pp = ref + (size_t)b * C * (HO * WO) + r;
    float4 s0 = {0.f, 0.f, 0.f, 0.f}, s1 = {0.f, 0.f, 0.f, 0.f};
#pragma unroll
    for (int c = 0; c < C; c += 2) {
      const float4 a = *(const float4*)&pp[(size_t)c * (HO * WO)];
      const float4 d = *(const float4*)&pp[(size_t)(c + 1) * (HO * WO)];
      s0.x += a.x; s0.y += a.y; s0.z += a.z; s0.w += a.w;
      s1.x += d.x; s1.y += d.y; s1.z += d.z; s1.w += d.w;
    }
    float4 o;
    o.x = (s0.x + s1.x) * (1.f / 64.f);
    o.y = (s0.y + s1.y) * (1.f / 64.f);
    o.z = (s0.z + s1.z) * (1.f / 64.f);
    o.w = (s0.w + s1.w) * (1.f / 64.f);
    *(float4*)&res[p] = o;
    return;
  }

  // ---- conv1 via MFMA ----
  const int blk = blockIdx.x;        // b*HI + h
  const int b = blk >> 6, h = blk & 63;

  const float* xrow = x + (size_t)b * C * (HI * WI) + h * WI;
  for (int i = tid; i < 512; i += 256) {      // 32 c-pairs x 16 px-quads
    const int c2 = i >> 4, px = (i & 15) * 4;
    const float4 lo = *(const float4*)&xrow[(size_t)(2 * c2) * (HI * WI) + px];
    const float4 hi = *(const float4*)&xrow[(size_t)(2 * c2 + 1) * (HI * WI) + px];
    uint4 pk;
    pk.x = packbf(lo.x, hi.x); pk.y = packbf(lo.y, hi.y);
    pk.z = packbf(lo.z, hi.z); pk.w = packbf(lo.w, hi.w);
    *(uint4*)&xP[c2][px] = pk;
  }
  for (int i = tid; i < 4096; i += 256) {     // W1 scale-folded -> bf16
    const int o = i >> 6;
    const float s = g[o] * rsqrtf(vv[o] + 1e-5f);
    W1s[o][i & 63] = (unsigned short)bf16rne(w1[i] * s);
  }
  if (tid < 64) {
    const float s = g[tid] * rsqrtf(vv[tid] + 1e-5f);
    s_bs1[tid] = cb[tid] * s + bb[tid] - mm[tid] * s;
  }
  __syncthreads();

  const int wid = tid >> 6;          // o-tile (16 o each)
  const int lane = tid & 63;
  const int lq = lane >> 4, ln = lane & 15;

  const short8 fa0 = *(const short8*)&W1s[wid * 16 + ln][lq * 8];       // k=0..31
  const short8 fa1 = *(const short8*)&W1s[wid * 16 + ln][32 + lq * 8];  // k=32..63

  f32x4 acc[4];
#pragma unroll
  for (int t = 0; t < 4; ++t) {
    const int px = t * 16 + ln;
    i32x4 b0, b1;
#pragma unroll
    for (int r = 0; r < 4; ++r) {
      b0[r] = (int)xP[lq * 4 + r][px];
      b1[r] = (int)xP[16 + lq * 4 + r][px];
    }
    acc[t] = (f32x4){0.f, 0.f, 0.f, 0.f};
    acc[t] = __builtin_amdgcn_mfma_f32_16x16x32_bf16(fa0, __builtin_bit_cast(short8, b0), acc[t], 0, 0, 0);
    acc[t] = __builtin_amdgcn_mfma_f32_16x16x32_bf16(fa1, __builtin_bit_cast(short8, b1), acc[t], 0, 0, 0);
  }

  // D layout: row(o_local) = lq*4 + r, col(w) = t*16 + ln
  const float4 bsv = *(const float4*)&s_bs1[wid * 16 + lq * 4];
  const float bs[4] = {bsv.x, bsv.y, bsv.z, bsv.w};
#pragma unroll
  for (int t = 0; t < 4; ++t) {
#pragma unroll
    for (int r = 0; r < 4; ++r) {
      const int o = wid * 16 + lq * 4 + r;
      const int w = t * 16 + ln;
      y1[(((size_t)(b * C + o)) * HI + h) * WI + w] = relu(acc[t][r] + bs[r]);
    }
  }
}

// ---------------------------------------------------------------------------
// Kernel 2 (main): one (b,h) full row per block. 1024 blocks, 256 threads.
//  - conv2 via bf16 MFMA (scale folded into W2s), D -> out2 in LDS
//  - mask phase -> 4 corner weights + invden per pixel
//  - epilogue: out = num*invden + relu(out2 + bs2)
// LDS: union(refsP+W2s, out2) 33.8 KB + misc ~4.4 KB = 38.2 KB -> 4 blk/CU.
// ---------------------------------------------------------------------------
__global__ __launch_bounds__(256, 4) void k_main(
    const float* __restrict__ ref, const float* __restrict__ res,
    const float* __restrict__ y1, const float* __restrict__ w2,
    const float* __restrict__ cb, const float* __restrict__ g,
    const float* __restrict__ bb, const float* __restrict__ mm,
    const float* __restrict__ vv, float* __restrict__ out) {
  __shared__ __align__(16) char u_mem[64 * 132 * 4];   // 33792 B union
  unsigned* refsP = (unsigned*)u_mem;                  // [32][132] c-pair bf16
  unsigned short* W2s = (unsigned short*)(u_mem + 32 * 132 * 4);  // [64][72]
  float* out2 = (float*)u_mem;                         // [64][132] conv2 result
  __shared__ float resr[3][130];
  __shared__ float s_wc[4][128];
  __shared__ float s_inv[128];
  __shared__ float s_bs[64];

  const int blk = blockIdx.x;        // b*HO + h
  const int b = blk >> 7, h = blk & 127;
  const int tid = threadIdx.x;

  const float* refrow = ref + (size_t)b * C * (HO * WO) + h * WO;
  for (int i = tid; i < 1024; i += 256) {     // 32 c-pairs x 32 px-quads
    const int c2 = i >> 5, px = (i & 31) * 4;
    const float4 lo = *(const float4*)&refrow[(size_t)(2 * c2) * (HO * WO) + px];
    const float4 hi = *(const float4*)&refrow[(size_t)(2 * c2 + 1) * (HO * WO) + px];
    uint4 pk;
    pk.x = packbf(lo.x, hi.x); pk.y = packbf(lo.y, hi.y);
    pk.z = packbf(lo.z, hi.z); pk.w = packbf(lo.w, hi.w);
    *(uint4*)&refsP[c2 * 132 + px] = pk;
  }
  for (int i = tid; i < 4096; i += 256) {     // W2 scale-folded -> bf16
    const int o = i >> 6;
    const float s = g[o] * rsqrtf(vv[o] + 1e-5f);
    W2s[o * 72 + (i & 63)] = (unsigned short)bf16rne(w2[i] * s);
  }
  if (tid < 64) {
    const float s = g[tid] * rsqrtf(vv[tid] + 1e-5f);
    s_bs[tid] = cb[tid] * s + bb[tid] - mm[tid] * s;
  }
  {
    const float* resb = res + (size_t)b * (HO * WO);
    for (int i = tid; i < 3 * 130; i += 256) {
      const int rr = i / 130, cc = i % 130;
      const int hh = h + rr - 1, ww = cc - 1;
      float v = 0.f;
      if (hh >= 0 && hh < HO && ww >= 0 && ww < WO)
        v = resb[hh * WO + ww];
      resr[rr][cc] = v;
    }
  }
  __syncthreads();   // b1

  // ---- MFMA conv2: 4 waves x (1 o-tile x 8 px-tiles), K=64 ----
  const int wid = tid >> 6;
  const int lane = tid & 63;
  const int lq = lane >> 4, ln = lane & 15;

  const short8 fa0 = *(const short8*)&W2s[(wid * 16 + ln) * 72 + lq * 8];
  const short8 fa1 = *(const short8*)&W2s[(wid * 16 + ln) * 72 + 32 + lq * 8];

  f32x4 acc[8];
#pragma unroll
  for (int t = 0; t < 8; ++t) {
    const int px = t * 16 + ln;
    i32x4 b0, b1;
#pragma unroll
    for (int r = 0; r < 4; ++r) {
      b0[r] = (int)refsP[(lq * 4 + r) * 132 + px];
      b1[r] = (int)refsP[(16 + lq * 4 + r) * 132 + px];
    }
    acc[t] = (f32x4){0.f, 0.f, 0.f, 0.f};
    acc[t] = __builtin_amdgcn_mfma_f32_16x16x32_bf16(fa0, __builtin_bit_cast(short8, b0), acc[t], 0, 0, 0);
    acc[t] = __builtin_amdgcn_mfma_f32_16x16x32_bf16(fa1, __builtin_bit_cast(short8, b1), acc[t], 0, 0, 0);
  }

  const int rlo = (h >= 1) ? ((h - 1) >> 1) : 0;

  // ---- mask phase: per-pixel corner weights (threads 0..127) ----
  if (tid < WO) {
    const int w = tid;
    float u[9];
#pragma unroll
    for (int dh = 0; dh < 3; ++dh)
#pragma unroll
      for (int dw = 0; dw < 3; ++dw)
        u[dh * 3 + dw] = resr[dh][w + dw];
    float sum = u[0];
#pragma unroll
    for (int k = 1; k < 9; ++k) sum += u[k];
    const float ua = sum * (1.f / 9.f);
    const bool ui = (u[4] - ua) > 0.f;

    const int clo = (w >= 1) ? ((w - 1) >> 1) : 0;
    float den = 0.f;
    float wc0 = 0.f, wc1 = 0.f, wc2 = 0.f, wc3 = 0.f;
#pragma unroll
    for (int dh = 0; dh < 3; ++dh) {
      const int hh = h + dh - 1;
      const bool hv = (hh >= 0) && (hh < HO);
      const int rs = hv ? ((hh >> 1) - rlo) : 0;
#pragma unroll
      for (int dw = 0; dw < 3; ++dw) {
        const bool up = (u[dh * 3 + dw] - ua) > 0.f;
        const float mk = (up == ui) ? 1.f : 0.f;
        den += mk;
        const int ww = w + dw - 1;
        const bool wv = (ww >= 0) && (ww < WO);
        const int cs = wv ? ((ww >> 1) - clo) : 0;
        const float t = (hv && wv) ? mk : 0.f;
        const float t0 = (rs == 0) ? t : 0.f;
        const float t1 = (rs == 1) ? t : 0.f;
        wc0 += (cs == 0) ? t0 : 0.f;
        wc1 += (cs == 1) ? t0 : 0.f;
        wc2 += (cs == 0) ? t1 : 0.f;
        wc3 += (cs == 1) ? t1 : 0.f;
      }
    }
    s_wc[0][w] = wc0; s_wc[1][w] = wc1; s_wc[2][w] = wc2; s_wc[3][w] = wc3;
    s_inv[w] = 1.f / (den + 1e-6f);
  }
  __syncthreads();   // b2: all refsP/W2s reads done, mask done

  // ---- D -> out2 (overwrites refsP/W2s union region) ----
#pragma unroll
  for (int t = 0; t < 8; ++t)
#pragma unroll
    for (int r = 0; r < 4; ++r)
      out2[(wid * 16 + lq * 4 + r) * 132 + t * 16 + ln] = acc[t][r];
  __syncthreads();   // b3

  // ---- epilogue: 8o x 4w per thread ----
  const int wg = tid & 31, og = tid >> 5;
  const int w4 = wg * 4, o8 = og * 8;

  const float4 wcv0 = *(const float4*)&s_wc[0][w4];
  const float4 wcv1 = *(const float4*)&s_wc[1][w4];
  const float4 wcv2 = *(const float4*)&s_wc[2][w4];
  const float4 wcv3 = *(const float4*)&s_wc[3][w4];
  const float4 invv = *(const float4*)&s_inv[w4];

  int r1 = rlo + 1; if (r1 > HI - 1) r1 = HI - 1;
  int cl[4], c1a[4];
#pragma unroll
  for (int j = 0; j < 4; ++j) {
    const int w = w4 + j;
    cl[j] = (w >= 1) ? ((w - 1) >> 1) : 0;
    c1a[j] = cl[j] + 1; if (c1a[j] > WI - 1) c1a[j] = WI - 1;
  }

  float bs8[8];
  *(float4*)&bs8[0] = *(const float4*)&s_bs[o8];
  *(float4*)&bs8[4] = *(const float4*)&s_bs[o8 + 4];

  const float* y1base = y1 + (size_t)(b * C + o8) * (HI * WI);
  float* outb = out + (size_t)(b * C + o8) * (HO * WO) + h * WO + w4;
#pragma unroll
  for (int j = 0; j < 8; ++j) {
    const float* r0p = y1base + (size_t)j * (HI * WI) + rlo * WI;
    const float* r1p = y1base + (size_t)j * (HI * WI) + r1 * WI;
    const float4 d = *(const float4*)&out2[(o8 + j) * 132 + w4];

    const float n0 = wcv0.x * r0p[cl[0]] + wcv1.x * r0p[c1a[0]] + wcv2.x * r1p[cl[0]] + wcv3.x * r1p[c1a[0]];
    const float n1 = wcv0.y * r0p[cl[1]] + wcv1.y * r0p[c1a[1]] + wcv2.y * r1p[cl[1]] + wcv3.y * r1p[c1a[1]];
    const float n2 = wcv0.z * r0p[cl[2]] + wcv1.z * r0p[c1a[2]] + wcv2.z * r1p[cl[2]] + wcv3.z * r1p[c1a[2]];
    const float n3 = wcv0.w * r0p[cl[3]] + wcv1.w * r0p[c1a[3]] + wcv2.w * r1p[cl[3]] + wcv3.w * r1p[c1a[3]];

    float4 v;
    v.x = n0 * invv.x + relu(d.x + bs8[j]);
    v.y = n1 * invv.y + relu(d.y + bs8[j]);
    v.z = n2 * invv.z + relu(d.z + bs8[j]);
    v.w = n3 * invv.w + relu(d.w + bs8[j]);
    *(float4*)(outb + (size_t)j * (HO * WO)) = v;
  }
}

// ---------------------------------------------------------------------------
extern "C" void kernel_launch(void* const* d_in, const int* in_sizes, int n_in,
                              void* d_out, int out_size, void* d_ws, size_t ws_size,
                              hipStream_t stream) {
  (void)in_sizes; (void)n_in; (void)out_size; (void)ws_size;
  const float* x   = (const float*)d_in[0];
  const float* ref = (const float*)d_in[1];
  const float* w1  = (const float*)d_in[2];
  const float* c1b = (const float*)d_in[3];
  const float* g1  = (const float*)d_in[4];
  const float* b1  = (const float*)d_in[5];
  const float* m1  = (const float*)d_in[6];
  const float* v1  = (const float*)d_in[7];
  const float* w2  = (const float*)d_in[8];
  const float* c2b = (const float*)d_in[9];
  const float* g2  = (const float*)d_in[10];
  const float* b2  = (const float*)d_in[11];
  const float* m2  = (const float*)d_in[12];
  const float* v2  = (const float*)d_in[13];
  float* out = (float*)d_out;

  float* y1  = (float*)d_ws;                       // 8 MB
  float* res = y1 + (size_t)B * C * HI * WI;       // 0.5 MB

  k_pre<<<512 + 128, 256, 0, stream>>>(x, w1, c1b, g1, b1, m1, v1, ref, y1, res);
  k_main<<<B * HO, 256, 0, stream>>>(ref, res, y1, w2, c2b, g2, b2, m2, v2, out);
}

// Round 4
// 138.456 us; speedup vs baseline: 1.0724x; 1.0117x over previous
//
#include <hip/hip_runtime.h>

// Problem dims (hardcoded per reference setup_inputs):
//   x:   (8, 64, 64, 64)  fp32
//   ref: (8, 64, 128, 128) fp32
//   out: (8, 64, 128, 128) fp32
#define B   8
#define C   64
#define HI  64
#define WI  64
#define HO  128
#define WO  128

using short8 = __attribute__((ext_vector_type(8))) short;
using f32x4  = __attribute__((ext_vector_type(4))) float;
using i32x4  = __attribute__((ext_vector_type(4))) int;

__device__ __forceinline__ float relu(float v) { return v > 0.f ? v : 0.f; }

// round-to-nearest-even f32 -> bf16 (low 16 bits of result)
__device__ __forceinline__ unsigned bf16rne(float x) {
  unsigned u = __float_as_uint(x);
  u += 0x7FFFu + ((u >> 16) & 1u);
  return u >> 16;
}
// pack two f32 -> bf16 pair (lo in bits [15:0], hi in bits [31:16])
__device__ __forceinline__ unsigned packbf(float lo, float hi) {
  unsigned ua = __float_as_uint(lo); ua += 0x7FFFu + ((ua >> 16) & 1u);
  unsigned ub = __float_as_uint(hi); ub += 0x7FFFu + ((ub >> 16) & 1u);
  return (ua >> 16) | (ub & 0xFFFF0000u);
}

// ---------------------------------------------------------------------------
// Kernel 1 (fused pre-pass):
//   blocks [0,512):   y1 = relu(W1s @ x + bs1) via bf16 MFMA, one (b,h) row.
//                     y1 stored CHANNEL-LAST: y1[b][h][w][ch] so k_main's
//                     4-corner gather reads contiguous float4 over ch.
//   blocks [512,640): res = channel-mean of ref, float4-vectorized
// ---------------------------------------------------------------------------
__global__ __launch_bounds__(256) void k_pre(
    const float* __restrict__ x, const float* __restrict__ w1,
    const float* __restrict__ cb, const float* __restrict__ g,
    const float* __restrict__ bb, const float* __restrict__ mm,
    const float* __restrict__ vv, const float* __restrict__ ref,
    float* __restrict__ y1, float* __restrict__ res) {
  __shared__ __align__(16) char u_mem[17920];
  unsigned* xP = (unsigned*)u_mem;                         // [32][68] c-pair bf16
  unsigned short* W1s = (unsigned short*)(u_mem + 8704);   // [64][72] bf16
  float* yo = (float*)u_mem;                               // [64 w][68 ch] (reused after b2)
  __shared__ float s_bs1[64];

  const int tid = threadIdx.x;

  if (blockIdx.x >= 512) {           // ---- res part (HBM-bound) ----
    const int p = ((blockIdx.x - 512) * 256 + tid) * 4;
    const int b = p >> 14;           // HO*WO = 16384
    const int r = p & 16383;
    const float* pp = ref + (size_t)b * C * (HO * WO) + r;
    float4 s0 = {0.f, 0.f, 0.f, 0.f}, s1 = {0.f, 0.f, 0.f, 0.f};
#pragma unroll
    for (int c = 0; c < C; c += 2) {
      const float4 a = *(const float4*)&pp[(size_t)c * (HO * WO)];
      const float4 d = *(const float4*)&pp[(size_t)(c + 1) * (HO * WO)];
      s0.x += a.x; s0.y += a.y; s0.z += a.z; s0.w += a.w;
      s1.x += d.x; s1.y += d.y; s1.z += d.z; s1.w += d.w;
    }
    float4 o;
    o.x = (s0.x + s1.x) * (1.f / 64.f);
    o.y = (s0.y + s1.y) * (1.f / 64.f);
    o.z = (s0.z + s1.z) * (1.f / 64.f);
    o.w = (s0.w + s1.w) * (1.f / 64.f);
    *(float4*)&res[p] = o;
    return;
  }

  // ---- conv1 via MFMA ----
  const int bx = blockIdx.x;
  const int b = bx & 7;              // XCD-affine (blockIdx%8 -> XCD heuristic)
  const int h = bx >> 3;             // 0..63

  const float* xrow = x + (size_t)b * C * (HI * WI) + h * WI;
  for (int i = tid; i < 512; i += 256) {      // 32 c-pairs x 16 px-quads
    const int c2 = i >> 4, px = (i & 15) * 4;
    const float4 lo = *(const float4*)&xrow[(size_t)(2 * c2) * (HI * WI) + px];
    const float4 hi = *(const float4*)&xrow[(size_t)(2 * c2 + 1) * (HI * WI) + px];
    uint4 pk;
    pk.x = packbf(lo.x, hi.x); pk.y = packbf(lo.y, hi.y);
    pk.z = packbf(lo.z, hi.z); pk.w = packbf(lo.w, hi.w);
    *(uint4*)&xP[c2 * 68 + px] = pk;
  }
  for (int i = tid; i < 4096; i += 256) {     // W1 scale-folded -> bf16
    const int o = i >> 6;
    const float s = g[o] * rsqrtf(vv[o] + 1e-5f);
    W1s[o * 72 + (i & 63)] = (unsigned short)bf16rne(w1[i] * s);
  }
  if (tid < 64) {
    const float s = g[tid] * rsqrtf(vv[tid] + 1e-5f);
    s_bs1[tid] = cb[tid] * s + bb[tid] - mm[tid] * s;
  }
  __syncthreads();   // b1

  const int wid = tid >> 6;          // o-tile (16 o each)
  const int lane = tid & 63;
  const int lq = lane >> 4, ln = lane & 15;

  const short8 fa0 = *(const short8*)&W1s[(wid * 16 + ln) * 72 + lq * 8];       // k=0..31
  const short8 fa1 = *(const short8*)&W1s[(wid * 16 + ln) * 72 + 32 + lq * 8];  // k=32..63

  f32x4 acc[4];
#pragma unroll
  for (int t = 0; t < 4; ++t) {
    const int px = t * 16 + ln;
    i32x4 b0, b1;
#pragma unroll
    for (int r = 0; r < 4; ++r) {
      b0[r] = (int)xP[(lq * 4 + r) * 68 + px];
      b1[r] = (int)xP[(16 + lq * 4 + r) * 68 + px];
    }
    acc[t] = (f32x4){0.f, 0.f, 0.f, 0.f};
    acc[t] = __builtin_amdgcn_mfma_f32_16x16x32_bf16(fa0, __builtin_bit_cast(short8, b0), acc[t], 0, 0, 0);
    acc[t] = __builtin_amdgcn_mfma_f32_16x16x32_bf16(fa1, __builtin_bit_cast(short8, b1), acc[t], 0, 0, 0);
  }

  // D layout: o_local = lq*4 + r, w = t*16 + ln.  Remap via LDS -> [w][ch]
  const float4 bsv = *(const float4*)&s_bs1[wid * 16 + lq * 4];
  const float bs[4] = {bsv.x, bsv.y, bsv.z, bsv.w};
  __syncthreads();   // b2: xP/W1s reads done, safe to reuse u_mem
#pragma unroll
  for (int t = 0; t < 4; ++t)
#pragma unroll
    for (int r = 0; r < 4; ++r)
      yo[(t * 16 + ln) * 68 + wid * 16 + lq * 4 + r] = relu(acc[t][r] + bs[r]);
  __syncthreads();   // b3

  float* yrow = y1 + ((size_t)(b * HI + h) * WI) * 64;   // [b][h][w][ch]
  for (int i = tid; i < 1024; i += 256) {
    const int w = i >> 4, o4 = (i & 15) * 4;
    *(float4*)&yrow[w * 64 + o4] = *(const float4*)&yo[w * 68 + o4];
  }
}

// ---------------------------------------------------------------------------
// Kernel 2 (main): one (b,h) full row per block; b = blockIdx&7 (XCD-affine
// so y1[b] (1 MB) and res[b] stay L2-resident on one XCD).
//  - conv2 via bf16 MFMA (scale folded into W2s), acc kept in regs
//  - mask phase -> 4 corner weights + invden per pixel
//  - epilogue straight from acc (MFMA C-layout): y1 corners are float4 over
//    ch (channel-last layout), out = num*invden + relu(acc + bs2)
// ---------------------------------------------------------------------------
__global__ __launch_bounds__(256, 4) void k_main(
    const float* __restrict__ ref, const float* __restrict__ res,
    const float* __restrict__ y1, const float* __restrict__ w2,
    const float* __restrict__ cb, const float* __restrict__ g,
    const float* __restrict__ bb, const float* __restrict__ mm,
    const float* __restrict__ vv, float* __restrict__ out) {
  __shared__ __align__(16) char u_mem[26112];
  unsigned* refsP = (unsigned*)u_mem;                       // [32][132] c-pair bf16
  unsigned short* W2s = (unsigned short*)(u_mem + 16896);   // [64][72] bf16
  __shared__ float resr[3][130];
  __shared__ float s_wc[4][128];
  __shared__ float s_inv[128];
  __shared__ float s_bs[64];

  const int bx = blockIdx.x;
  const int b = bx & 7;              // XCD-affine
  const int h = bx >> 3;             // 0..127
  const int tid = threadIdx.x;

  const float* refrow = ref + (size_t)b * C * (HO * WO) + h * WO;
  for (int i = tid; i < 1024; i += 256) {     // 32 c-pairs x 32 px-quads
    const int c2 = i >> 5, px = (i & 31) * 4;
    const float4 lo = *(const float4*)&refrow[(size_t)(2 * c2) * (HO * WO) + px];
    const float4 hi = *(const float4*)&refrow[(size_t)(2 * c2 + 1) * (HO * WO) + px];
    uint4 pk;
    pk.x = packbf(lo.x, hi.x); pk.y = packbf(lo.y, hi.y);
    pk.z = packbf(lo.z, hi.z); pk.w = packbf(lo.w, hi.w);
    *(uint4*)&refsP[c2 * 132 + px] = pk;
  }
  for (int i = tid; i < 4096; i += 256) {     // W2 scale-folded -> bf16
    const int o = i >> 6;
    const float s = g[o] * rsqrtf(vv[o] + 1e-5f);
    W2s[o * 72 + (i & 63)] = (unsigned short)bf16rne(w2[i] * s);
  }
  if (tid < 64) {
    const float s = g[tid] * rsqrtf(vv[tid] + 1e-5f);
    s_bs[tid] = cb[tid] * s + bb[tid] - mm[tid] * s;
  }
  {
    const float* resb = res + (size_t)b * (HO * WO);
    for (int i = tid; i < 3 * 130; i += 256) {
      const int rr = i / 130, cc = i % 130;
      const int hh = h + rr - 1, ww = cc - 1;
      float v = 0.f;
      if (hh >= 0 && hh < HO && ww >= 0 && ww < WO)
        v = resb[hh * WO + ww];
      resr[rr][cc] = v;
    }
  }
  __syncthreads();   // b1

  // ---- MFMA conv2: 4 waves x (1 o-tile x 8 px-tiles), K=64 ----
  const int wid = tid >> 6;
  const int lane = tid & 63;
  const int lq = lane >> 4, ln = lane & 15;

  const short8 fa0 = *(const short8*)&W2s[(wid * 16 + ln) * 72 + lq * 8];
  const short8 fa1 = *(const short8*)&W2s[(wid * 16 + ln) * 72 + 32 + lq * 8];

  f32x4 acc[8];
#pragma unroll
  for (int t = 0; t < 8; ++t) {
    const int px = t * 16 + ln;
    i32x4 b0, b1;
#pragma unroll
    for (int r = 0; r < 4; ++r) {
      b0[r] = (int)refsP[(lq * 4 + r) * 132 + px];
      b1[r] = (int)refsP[(16 + lq * 4 + r) * 132 + px];
    }
    acc[t] = (f32x4){0.f, 0.f, 0.f, 0.f};
    acc[t] = __builtin_amdgcn_mfma_f32_16x16x32_bf16(fa0, __builtin_bit_cast(short8, b0), acc[t], 0, 0, 0);
    acc[t] = __builtin_amdgcn_mfma_f32_16x16x32_bf16(fa1, __builtin_bit_cast(short8, b1), acc[t], 0, 0, 0);
  }

  const int rlo = (h >= 1) ? ((h - 1) >> 1) : 0;

  // ---- mask phase: per-pixel corner weights (threads 0..127) ----
  if (tid < WO) {
    const int w = tid;
    float u[9];
#pragma unroll
    for (int dh = 0; dh < 3; ++dh)
#pragma unroll
      for (int dw = 0; dw < 3; ++dw)
        u[dh * 3 + dw] = resr[dh][w + dw];
    float sum = u[0];
#pragma unroll
    for (int k = 1; k < 9; ++k) sum += u[k];
    const float ua = sum * (1.f / 9.f);
    const bool ui = (u[4] - ua) > 0.f;

    const int clo = (w >= 1) ? ((w - 1) >> 1) : 0;
    float den = 0.f;
    float wc0 = 0.f, wc1 = 0.f, wc2 = 0.f, wc3 = 0.f;
#pragma unroll
    for (int dh = 0; dh < 3; ++dh) {
      const int hh = h + dh - 1;
      const bool hv = (hh >= 0) && (hh < HO);
      const int rs = hv ? ((hh >> 1) - rlo) : 0;
#pragma unroll
      for (int dw = 0; dw < 3; ++dw) {
        const bool up = (u[dh * 3 + dw] - ua) > 0.f;
        const float mk = (up == ui) ? 1.f : 0.f;
        den += mk;
        const int ww = w + dw - 1;
        const bool wv = (ww >= 0) && (ww < WO);
        const int cs = wv ? ((ww >> 1) - clo) : 0;
        const float t = (hv && wv) ? mk : 0.f;
        const float t0 = (rs == 0) ? t : 0.f;
        const float t1 = (rs == 1) ? t : 0.f;
        wc0 += (cs == 0) ? t0 : 0.f;
        wc1 += (cs == 1) ? t0 : 0.f;
        wc2 += (cs == 0) ? t1 : 0.f;
        wc3 += (cs == 1) ? t1 : 0.f;
      }
    }
    s_wc[0][w] = wc0; s_wc[1][w] = wc1; s_wc[2][w] = wc2; s_wc[3][w] = wc3;
    s_inv[w] = 1.f / (den + 1e-6f);
  }
  __syncthreads();   // b2: mask ready

  // ---- epilogue straight from acc: o = wid*16+lq*4+r, px = t*16+ln ----
  const int obase = wid * 16 + lq * 4;
  float bs4[4];
  *(float4*)bs4 = *(const float4*)&s_bs[obase];

  int r1 = rlo + 1; if (r1 > HI - 1) r1 = HI - 1;
  const float* y1b = y1 + (size_t)b * (HI * WI * 64);     // [h][w][ch]
  const float* rowp0 = y1b + (size_t)(rlo * WI) * 64;
  const float* rowp1 = y1b + (size_t)(r1 * WI) * 64;

#pragma unroll
  for (int t = 0; t < 8; ++t) {
    const int px = t * 16 + ln;
    const int cl = (px >= 1) ? ((px - 1) >> 1) : 0;
    int c1 = cl + 1; if (c1 > WI - 1) c1 = WI - 1;
    const float wc0 = s_wc[0][px], wc1 = s_wc[1][px];
    const float wc2 = s_wc[2][px], wc3 = s_wc[3][px];
    const float inv = s_inv[px];

    const float4 a00 = *(const float4*)&rowp0[cl * 64 + obase];
    const float4 a01 = *(const float4*)&rowp0[c1 * 64 + obase];
    const float4 a10 = *(const float4*)&rowp1[cl * 64 + obase];
    const float4 a11 = *(const float4*)&rowp1[c1 * 64 + obase];

    float* op = out + (size_t)(b * C + obase) * (HO * WO) + h * WO + px;
#pragma unroll
    for (int r = 0; r < 4; ++r) {
      const float n = wc0 * ((const float*)&a00)[r] + wc1 * ((const float*)&a01)[r]
                    + wc2 * ((const float*)&a10)[r] + wc3 * ((const float*)&a11)[r];
      op[(size_t)r * (HO * WO)] = n * inv + relu(acc[t][r] + bs4[r]);
    }
  }
}

// ---------------------------------------------------------------------------
extern "C" void kernel_launch(void* const* d_in, const int* in_sizes, int n_in,
                              void* d_out, int out_size, void* d_ws, size_t ws_size,
                              hipStream_t stream) {
  (void)in_sizes; (void)n_in; (void)out_size; (void)ws_size;
  const float* x   = (const float*)d_in[0];
  const float* ref = (const float*)d_in[1];
  const float* w1  = (const float*)d_in[2];
  const float* c1b = (const float*)d_in[3];
  const float* g1  = (const float*)d_in[4];
  const float* b1  = (const float*)d_in[5];
  const float* m1  = (const float*)d_in[6];
  const float* v1  = (const float*)d_in[7];
  const float* w2  = (const float*)d_in[8];
  const float* c2b = (const float*)d_in[9];
  const float* g2  = (const float*)d_in[10];
  const float* b2  = (const float*)d_in[11];
  const float* m2  = (const float*)d_in[12];
  const float* v2  = (const float*)d_in[13];
  float* out = (float*)d_out;

  float* y1  = (float*)d_ws;                       // 8 MB, [b][h][w][ch]
  float* res = y1 + (size_t)B * C * HI * WI;       // 0.5 MB

  k_pre<<<512 + 128, 256, 0, stream>>>(x, w1, c1b, g1, b1, m1, v1, ref, y1, res);
  k_main<<<B * HO, 256, 0, stream>>>(ref, res, y1, w2, c2b, g2, b2, m2, v2, out);
}